// Round 1
// baseline (150.761 us; speedup 1.0000x reference)
//
#include <hip/hip_runtime.h>

#define BB 4
#define TT 4096
#define CUT 2048
#define CE 1024
#define HD 64
#define SCALE 0.03125f   // 1024^-0.5

typedef unsigned short u16;
typedef __attribute__((ext_vector_type(8))) short bf16x8;
typedef __attribute__((ext_vector_type(4))) float f32x4;

__device__ __forceinline__ u16 f2b(float f) {
  union { float f; unsigned u; } v; v.f = f;
  unsigned r = v.u + 0x7fffu + ((v.u >> 16) & 1u);   // RNE to bf16
  return (u16)(r >> 16);
}

// ---- Kernel 1: W3T[(m*64+n)*1024 + k] = bf16(W_m[k][n]),  m: 0=K,1=V,2=Q ----
__global__ void wtrans_k(const float* __restrict__ Wk, const float* __restrict__ Wv,
                         const float* __restrict__ Wq, u16* __restrict__ w3t) {
  int id = blockIdx.x * 256 + threadIdx.x;     // 196608 total
  int k = id & 1023;
  int n = (id >> 10) & 63;
  int m = id >> 16;
  const float* W = (m == 0) ? Wk : (m == 1) ? Wv : Wq;
  w3t[id] = f2b(W[k * 64 + n]);
}

// ---- Kernel 2: QKV projection, bf16 MFMA, fp32 accum ----
// Block: 256 thr (4 waves), 64 rows/block; wave handles 16 rows.
__launch_bounds__(256)
__global__ void proj_k(const float* __restrict__ x, const u16* __restrict__ w3t,
                       const float* __restrict__ bk, const float* __restrict__ bv,
                       const float* __restrict__ bq,
                       u16* __restrict__ Kb, u16* __restrict__ Vb, u16* __restrict__ Qb) {
  __shared__ u16 wlds[192][72];                 // [n3][BK=64 (+8 pad)]
  const int tid  = threadIdx.x;
  const int lane = tid & 63;
  const int wv   = tid >> 6;
  const int l15  = lane & 15;
  const int g    = lane >> 4;
  const int row  = blockIdx.x * 64 + wv * 16 + l15;   // A-frag row
  const float* xrow = x + (size_t)row * CE;

  f32x4 acc[3][4];
  #pragma unroll
  for (int m = 0; m < 3; ++m)
    #pragma unroll
    for (int nt = 0; nt < 4; ++nt) acc[m][nt] = (f32x4){0.f, 0.f, 0.f, 0.f};

  const int srow = tid >> 3;                    // 0..31
  const int scol = (tid & 7) * 8;               // 0..56

  for (int kb = 0; kb < 16; ++kb) {
    __syncthreads();
    #pragma unroll
    for (int p = 0; p < 6; ++p) {               // stage W chunk [192][64] -> LDS
      int n3 = p * 32 + srow;
      *(bf16x8*)&wlds[n3][scol] = *(const bf16x8*)&w3t[n3 * 1024 + kb * 64 + scol];
    }
    __syncthreads();
    #pragma unroll
    for (int kc = 0; kc < 2; ++kc) {
      const float* xp = xrow + kb * 64 + kc * 32 + g * 8;
      f32x4 xa = *(const f32x4*)xp;
      f32x4 xb = *(const f32x4*)(xp + 4);
      bf16x8 a;
      #pragma unroll
      for (int j = 0; j < 4; ++j) { a[j] = (short)f2b(xa[j]); a[j + 4] = (short)f2b(xb[j]); }
      #pragma unroll
      for (int m = 0; m < 3; ++m)
        #pragma unroll
        for (int nt = 0; nt < 4; ++nt) {
          bf16x8 bfr = *(const bf16x8*)&wlds[m * 64 + nt * 16 + l15][kc * 32 + g * 8];
          acc[m][nt] = __builtin_amdgcn_mfma_f32_16x16x32_bf16(a, bfr, acc[m][nt], 0, 0, 0);
        }
    }
  }

  const int orow0 = blockIdx.x * 64 + wv * 16 + g * 4;   // C/D: row=(lane>>4)*4+r, col=l15
  #pragma unroll
  for (int m = 0; m < 3; ++m) {
    const float* bias = (m == 0) ? bk : (m == 1) ? bv : bq;
    #pragma unroll
    for (int nt = 0; nt < 4; ++nt) {
      int col = nt * 16 + l15;
      float bc = bias[col];
      #pragma unroll
      for (int r = 0; r < 4; ++r) {
        int orow = orow0 + r;
        u16 h = f2b(acc[m][nt][r] + bc);
        if (m == 0)      Kb[(size_t)orow * HD + col] = h;
        else if (m == 1) Vb[(size_t)orow * HD + col] = h;
        else {
          int t = orow & (TT - 1);
          if (t >= CUT) Qb[((size_t)(orow >> 12) * CUT + (t - CUT)) * HD + col] = h;
        }
      }
    }
  }
}

// ---- Kernel 3: flash attention, swapped-QK (S^T) online softmax ----
// Block: 128 thr (2 waves), 32 q-rows/block; wave = 16 q-rows. Grid (64, B).
__launch_bounds__(128)
__global__ void attn_k(const u16* __restrict__ Qb, const u16* __restrict__ Kb,
                       const u16* __restrict__ Vb, float* __restrict__ out) {
  __shared__ u16 VT[64][72];                    // V^T tile: [d][key]
  __shared__ u16 PL[2][16][72];                 // per-wave P: [q][key]
  const int tid  = threadIdx.x;
  const int lane = tid & 63;
  const int wv   = tid >> 6;
  const int l15  = lane & 15;
  const int g    = lane >> 4;
  const int i0   = blockIdx.x * 32;
  const int b    = blockIdx.y;
  const int iw   = i0 + wv * 16;

  const int qabs = CUT + iw + l15;              // abs pos of this lane's q column (S^T)

  const u16* qrow = Qb + ((size_t)b * CUT + iw + l15) * HD;
  bf16x8 qf0 = *(const bf16x8*)&qrow[g * 8];
  bf16x8 qf1 = *(const bf16x8*)&qrow[32 + g * 8];

  f32x4 o[4];
  #pragma unroll
  for (int dt = 0; dt < 4; ++dt) o[dt] = (f32x4){0.f, 0.f, 0.f, 0.f};
  float m_run = -1e30f, l_run = 0.f;

  const int kv_end = CUT + i0 + 32;
  const u16* Kbase = Kb + (size_t)b * TT * HD;
  const u16* Vbase = Vb + (size_t)b * TT * HD;
  const int skey = tid >> 1;
  const int sdg  = (tid & 1) * 32;

  for (int kv0 = 0; kv0 < kv_end; kv0 += 64) {
    __syncthreads();
    {   // stage V^T for keys kv0..kv0+63
      const u16* vr = Vbase + (size_t)(kv0 + skey) * HD + sdg;
      bf16x8 v0 = *(const bf16x8*)&vr[0];
      bf16x8 v1 = *(const bf16x8*)&vr[8];
      bf16x8 v2 = *(const bf16x8*)&vr[16];
      bf16x8 v3 = *(const bf16x8*)&vr[24];
      #pragma unroll
      for (int j = 0; j < 8; ++j) {
        VT[sdg + j][skey]      = (u16)v0[j];
        VT[sdg + 8 + j][skey]  = (u16)v1[j];
        VT[sdg + 16 + j][skey] = (u16)v2[j];
        VT[sdg + 24 + j][skey] = (u16)v3[j];
      }
    }
    __syncthreads();

    f32x4 st[4];                                // S^T: lane holds q=l15, key=g*4+r per tile
    #pragma unroll
    for (int kt = 0; kt < 4; ++kt) {
      const u16* krow = Kbase + (size_t)(kv0 + kt * 16 + l15) * HD;
      bf16x8 kf0 = *(const bf16x8*)&krow[g * 8];
      bf16x8 kf1 = *(const bf16x8*)&krow[32 + g * 8];
      f32x4 s = (f32x4){0.f, 0.f, 0.f, 0.f};
      s = __builtin_amdgcn_mfma_f32_16x16x32_bf16(kf0, qf0, s, 0, 0, 0);
      s = __builtin_amdgcn_mfma_f32_16x16x32_bf16(kf1, qf1, s, 0, 0, 0);
      st[kt] = s;
    }

    float mt = -1e30f;
    #pragma unroll
    for (int kt = 0; kt < 4; ++kt)
      #pragma unroll
      for (int r = 0; r < 4; ++r) {
        int key = kv0 + kt * 16 + g * 4 + r;
        float sv = (key <= qabs) ? st[kt][r] * SCALE : -1e30f;
        st[kt][r] = sv;
        mt = fmaxf(mt, sv);
      }
    mt = fmaxf(mt, __shfl_xor(mt, 16));
    mt = fmaxf(mt, __shfl_xor(mt, 32));
    float m_new = fmaxf(m_run, mt);
    float alpha = __expf(m_run - m_new);
    float tsum = 0.f;
    #pragma unroll
    for (int kt = 0; kt < 4; ++kt)
      #pragma unroll
      for (int r = 0; r < 4; ++r) {
        float p = __expf(st[kt][r] - m_new);
        st[kt][r] = p;
        tsum += p;
      }
    tsum += __shfl_xor(tsum, 16);
    tsum += __shfl_xor(tsum, 32);
    l_run = l_run * alpha + tsum;
    m_run = m_new;

    float ar0 = __shfl(alpha, g * 4 + 0);       // alpha for O rows (row=g*4+r layout)
    float ar1 = __shfl(alpha, g * 4 + 1);
    float ar2 = __shfl(alpha, g * 4 + 2);
    float ar3 = __shfl(alpha, g * 4 + 3);
    #pragma unroll
    for (int dt = 0; dt < 4; ++dt) {
      o[dt][0] *= ar0; o[dt][1] *= ar1; o[dt][2] *= ar2; o[dt][3] *= ar3;
    }

    #pragma unroll
    for (int kt = 0; kt < 4; ++kt)              // P -> LDS (bf16), wave-private
      #pragma unroll
      for (int r = 0; r < 4; ++r)
        PL[wv][l15][kt * 16 + g * 4 + r] = f2b(st[kt][r]);

    #pragma unroll
    for (int c = 0; c < 2; ++c) {               // O += P @ V
      bf16x8 pa = *(const bf16x8*)&PL[wv][l15][c * 32 + g * 8];
      #pragma unroll
      for (int dt = 0; dt < 4; ++dt) {
        bf16x8 vf = *(const bf16x8*)&VT[dt * 16 + l15][c * 32 + g * 8];
        o[dt] = __builtin_amdgcn_mfma_f32_16x16x32_bf16(pa, vf, o[dt], 0, 0, 0);
      }
    }
  }

  float linv = 1.f / l_run;
  float lr[4];
  lr[0] = __shfl(linv, g * 4 + 0);
  lr[1] = __shfl(linv, g * 4 + 1);
  lr[2] = __shfl(linv, g * 4 + 2);
  lr[3] = __shfl(linv, g * 4 + 3);
  #pragma unroll
  for (int dt = 0; dt < 4; ++dt)
    #pragma unroll
    for (int r = 0; r < 4; ++r)
      out[((size_t)b * CUT + iw + g * 4 + r) * HD + dt * 16 + l15] = o[dt][r] * lr[r];
}

extern "C" void kernel_launch(void* const* d_in, const int* in_sizes, int n_in,
                              void* d_out, int out_size, void* d_ws, size_t ws_size,
                              hipStream_t stream) {
  const float* x  = (const float*)d_in[0];
  const float* Wq = (const float*)d_in[1];
  const float* bq = (const float*)d_in[2];
  const float* Wk = (const float*)d_in[3];
  const float* bk = (const float*)d_in[4];
  const float* Wv = (const float*)d_in[5];
  const float* bv = (const float*)d_in[6];
  float* out = (float*)d_out;

  u16* Kb  = (u16*)d_ws;                               // [B*T*64]   bf16
  u16* Vb  = Kb + (size_t)BB * TT * HD;                // [B*T*64]
  u16* Qb  = Vb + (size_t)BB * TT * HD;                // [B*CUT*64]
  u16* W3T = Qb + (size_t)BB * CUT * HD;               // [192*1024]

  wtrans_k<<<768, 256, 0, stream>>>(Wk, Wv, Wq, W3T);
  proj_k<<<256, 256, 0, stream>>>(x, W3T, bk, bv, bq, Kb, Vb, Qb);
  attn_k<<<dim3(64, BB), 128, 0, stream>>>(Qb, Kb, Vb, out);
}

// Round 2
// 107.046 us; speedup vs baseline: 1.4084x; 1.4084x over previous
//
#include <hip/hip_runtime.h>

#define BB 4
#define TT 4096
#define CUT 2048
#define CE 1024
#define HD 64
#define SCALE 0.03125f   // 1024^-0.5

typedef unsigned short u16;
typedef __attribute__((ext_vector_type(8))) short bf16x8;
typedef __attribute__((ext_vector_type(4))) float f32x4;

__device__ __forceinline__ u16 f2b(float f) {
  union { float f; unsigned u; } v; v.f = f;
  unsigned r = v.u + 0x7fffu + ((v.u >> 16) & 1u);   // RNE to bf16
  return (u16)(r >> 16);
}

// ---- Kernel 1: W3T[(m*64+n)*1024 + k] = bf16(W_m[k][n]),  m: 0=K,1=V,2=Q ----
__global__ void wtrans_k(const float* __restrict__ Wk, const float* __restrict__ Wv,
                         const float* __restrict__ Wq, u16* __restrict__ w3t) {
  int id = blockIdx.x * 256 + threadIdx.x;     // 196608 total
  int k = id & 1023;
  int n = (id >> 10) & 63;
  int m = id >> 16;
  const float* W = (m == 0) ? Wk : (m == 1) ? Wv : Wq;
  w3t[id] = f2b(W[k * 64 + n]);
}

// ---- Kernel 2: QKV projection, bf16 MFMA, fp32 accum ----
__launch_bounds__(256)
__global__ void proj_k(const float* __restrict__ x, const u16* __restrict__ w3t,
                       const float* __restrict__ bk, const float* __restrict__ bv,
                       const float* __restrict__ bq,
                       u16* __restrict__ Kb, u16* __restrict__ Vb, u16* __restrict__ Qb) {
  __shared__ u16 wlds[192][72];                 // [n3][BK=64 (+8 pad)]
  const int tid  = threadIdx.x;
  const int lane = tid & 63;
  const int wv   = tid >> 6;
  const int l15  = lane & 15;
  const int g    = lane >> 4;
  const int row  = blockIdx.x * 64 + wv * 16 + l15;   // A-frag row
  const float* xrow = x + (size_t)row * CE;

  f32x4 acc[3][4];
  #pragma unroll
  for (int m = 0; m < 3; ++m)
    #pragma unroll
    for (int nt = 0; nt < 4; ++nt) acc[m][nt] = (f32x4){0.f, 0.f, 0.f, 0.f};

  const int srow = tid >> 3;                    // 0..31
  const int scol = (tid & 7) * 8;               // 0..56

  for (int kb = 0; kb < 16; ++kb) {
    __syncthreads();
    #pragma unroll
    for (int p = 0; p < 6; ++p) {               // stage W chunk [192][64] -> LDS
      int n3 = p * 32 + srow;
      *(bf16x8*)&wlds[n3][scol] = *(const bf16x8*)&w3t[n3 * 1024 + kb * 64 + scol];
    }
    __syncthreads();
    #pragma unroll
    for (int kc = 0; kc < 2; ++kc) {
      const float* xp = xrow + kb * 64 + kc * 32 + g * 8;
      f32x4 xa = *(const f32x4*)xp;
      f32x4 xb = *(const f32x4*)(xp + 4);
      bf16x8 a;
      #pragma unroll
      for (int j = 0; j < 4; ++j) { a[j] = (short)f2b(xa[j]); a[j + 4] = (short)f2b(xb[j]); }
      #pragma unroll
      for (int m = 0; m < 3; ++m)
        #pragma unroll
        for (int nt = 0; nt < 4; ++nt) {
          bf16x8 bfr = *(const bf16x8*)&wlds[m * 64 + nt * 16 + l15][kc * 32 + g * 8];
          acc[m][nt] = __builtin_amdgcn_mfma_f32_16x16x32_bf16(a, bfr, acc[m][nt], 0, 0, 0);
        }
    }
  }

  const int orow0 = blockIdx.x * 64 + wv * 16 + g * 4;   // C/D: row=(lane>>4)*4+r, col=l15
  #pragma unroll
  for (int m = 0; m < 3; ++m) {
    const float* bias = (m == 0) ? bk : (m == 1) ? bv : bq;
    #pragma unroll
    for (int nt = 0; nt < 4; ++nt) {
      int col = nt * 16 + l15;
      float bc = bias[col];
      #pragma unroll
      for (int r = 0; r < 4; ++r) {
        int orow = orow0 + r;
        u16 h = f2b(acc[m][nt][r] + bc);
        if (m == 0)      Kb[(size_t)orow * HD + col] = h;
        else if (m == 1) Vb[(size_t)orow * HD + col] = h;
        else {
          int t = orow & (TT - 1);
          if (t >= CUT) Qb[((size_t)(orow >> 12) * CUT + (t - CUT)) * HD + col] = h;
        }
      }
    }
  }
}

// ---- Kernel 2b: VT[b][d][t] = Vb[b][t][d]  (bf16 global transpose, L2-resident) ----
__global__ void vtrans_k(const u16* __restrict__ Vb, u16* __restrict__ VTg) {
  int id = blockIdx.x * 256 + threadIdx.x;     // 131072 total
  int t8 = id & 511;                           // 8-token group
  int d  = (id >> 9) & 63;
  int b  = id >> 15;
  const u16* src = Vb + ((size_t)b * TT + t8 * 8) * HD + d;
  bf16x8 vv;
  #pragma unroll
  for (int j = 0; j < 8; ++j) vv[j] = (short)src[j * HD];
  *(bf16x8*)&VTg[((size_t)b * HD + d) * TT + t8 * 8] = vv;
}

// ---- Kernel 3: flash attention, swapped-QK, 8-way KV-split per q-tile ----
// Block: 512 thr (8 waves) = ONE 16-query tile; wave wv owns chunks c=wv,wv+8,...
// No barriers in the main loop; one __syncthreads before the LDS combine.
__launch_bounds__(512)
__global__ void attn_k(const u16* __restrict__ Qb, const u16* __restrict__ Kb,
                       const u16* __restrict__ VTg, float* __restrict__ out) {
  __shared__ u16 PL[8][16][72];                 // per-wave P: [q][key]
  __shared__ float OO[8][16][68];               // per-wave unnormalized O: [q][d]
  __shared__ float OM[8][16];                   // per-wave running max per q
  __shared__ float OLs[8][16];                  // per-wave running sum per q
  const int tid  = threadIdx.x;
  const int lane = tid & 63;
  const int wv   = tid >> 6;
  const int l15  = lane & 15;
  const int g    = lane >> 4;
  const int i0   = blockIdx.x * 16;
  const int b    = blockIdx.y;

  const int qabs = CUT + i0 + l15;              // abs pos of this lane's q column (S^T)

  const u16* qrow = Qb + ((size_t)b * CUT + i0 + l15) * HD;
  bf16x8 qf0 = *(const bf16x8*)&qrow[g * 8];
  bf16x8 qf1 = *(const bf16x8*)&qrow[32 + g * 8];

  f32x4 o[4];
  #pragma unroll
  for (int dt = 0; dt < 4; ++dt) o[dt] = (f32x4){0.f, 0.f, 0.f, 0.f};
  float m_run = -1e30f, l_run = 0.f;

  const int kv_end = CUT + i0 + 16;
  const int nch = (kv_end + 63) >> 6;           // 33..64 chunks; every wave gets >=4
  const u16* Kbase = Kb + (size_t)b * TT * HD;
  const u16* Vbase = VTg + (size_t)b * HD * TT;

  for (int c = wv; c < nch; c += 8) {
    const int kv0 = c << 6;

    f32x4 st[4];                                // S^T: lane holds q=l15, key=g*4+r
    #pragma unroll
    for (int kt = 0; kt < 4; ++kt) {
      const u16* krow = Kbase + (size_t)(kv0 + kt * 16 + l15) * HD;
      bf16x8 kf0 = *(const bf16x8*)&krow[g * 8];
      bf16x8 kf1 = *(const bf16x8*)&krow[32 + g * 8];
      f32x4 s = (f32x4){0.f, 0.f, 0.f, 0.f};
      s = __builtin_amdgcn_mfma_f32_16x16x32_bf16(kf0, qf0, s, 0, 0, 0);
      s = __builtin_amdgcn_mfma_f32_16x16x32_bf16(kf1, qf1, s, 0, 0, 0);
      st[kt] = s;
    }

    float mt = -1e30f;
    #pragma unroll
    for (int kt = 0; kt < 4; ++kt)
      #pragma unroll
      for (int r = 0; r < 4; ++r) {
        int key = kv0 + kt * 16 + g * 4 + r;
        float sv = (key <= qabs) ? st[kt][r] * SCALE : -1e30f;
        st[kt][r] = sv;
        mt = fmaxf(mt, sv);
      }
    mt = fmaxf(mt, __shfl_xor(mt, 16));
    mt = fmaxf(mt, __shfl_xor(mt, 32));
    float m_new = fmaxf(m_run, mt);
    float alpha = __expf(m_run - m_new);
    float tsum = 0.f;
    #pragma unroll
    for (int kt = 0; kt < 4; ++kt)
      #pragma unroll
      for (int r = 0; r < 4; ++r) {
        float p = __expf(st[kt][r] - m_new);
        st[kt][r] = p;
        tsum += p;
      }
    tsum += __shfl_xor(tsum, 16);
    tsum += __shfl_xor(tsum, 32);
    l_run = l_run * alpha + tsum;
    m_run = m_new;

    float ar0 = __shfl(alpha, g * 4 + 0);       // alpha for O rows (row=g*4+r layout)
    float ar1 = __shfl(alpha, g * 4 + 1);
    float ar2 = __shfl(alpha, g * 4 + 2);
    float ar3 = __shfl(alpha, g * 4 + 3);
    #pragma unroll
    for (int dt = 0; dt < 4; ++dt) {
      o[dt][0] *= ar0; o[dt][1] *= ar1; o[dt][2] *= ar2; o[dt][3] *= ar3;
    }

    #pragma unroll
    for (int kt = 0; kt < 4; ++kt)              // P -> LDS (bf16), wave-private
      #pragma unroll
      for (int r = 0; r < 4; ++r)
        PL[wv][l15][kt * 16 + g * 4 + r] = f2b(st[kt][r]);

    #pragma unroll
    for (int c2 = 0; c2 < 2; ++c2) {            // O += P @ V (V^T frags direct from L2)
      bf16x8 pa = *(const bf16x8*)&PL[wv][l15][c2 * 32 + g * 8];
      #pragma unroll
      for (int dt = 0; dt < 4; ++dt) {
        bf16x8 vf = *(const bf16x8*)&Vbase[(size_t)(dt * 16 + l15) * TT + kv0 + c2 * 32 + g * 8];
        o[dt] = __builtin_amdgcn_mfma_f32_16x16x32_bf16(pa, vf, o[dt], 0, 0, 0);
      }
    }
  }

  // ---- publish per-wave partials ----
  if (lane < 16) { OM[wv][l15] = m_run; OLs[wv][l15] = l_run; }
  #pragma unroll
  for (int dt = 0; dt < 4; ++dt)
    #pragma unroll
    for (int r = 0; r < 4; ++r)
      OO[wv][g * 4 + r][dt * 16 + l15] = o[dt][r];
  __syncthreads();

  // ---- combine across the 8 KV-split waves ----
  #pragma unroll
  for (int e = tid; e < 1024; e += 512) {
    int q = e >> 6, d = e & 63;
    float M = OM[0][q];
    #pragma unroll
    for (int w = 1; w < 8; ++w) M = fmaxf(M, OM[w][q]);
    float L = 0.f, O = 0.f;
    #pragma unroll
    for (int w = 0; w < 8; ++w) {
      float s = __expf(OM[w][q] - M);
      L += OLs[w][q] * s;
      O += OO[w][q][d] * s;
    }
    out[((size_t)b * CUT + i0 + q) * HD + d] = O / L;
  }
}

extern "C" void kernel_launch(void* const* d_in, const int* in_sizes, int n_in,
                              void* d_out, int out_size, void* d_ws, size_t ws_size,
                              hipStream_t stream) {
  const float* x  = (const float*)d_in[0];
  const float* Wq = (const float*)d_in[1];
  const float* bq = (const float*)d_in[2];
  const float* Wk = (const float*)d_in[3];
  const float* bk = (const float*)d_in[4];
  const float* Wv = (const float*)d_in[5];
  const float* bv = (const float*)d_in[6];
  float* out = (float*)d_out;

  u16* Kb  = (u16*)d_ws;                               // [B*T*64]   bf16
  u16* Vb  = Kb + (size_t)BB * TT * HD;                // [B*T*64]
  u16* Qb  = Vb + (size_t)BB * TT * HD;                // [B*CUT*64]
  u16* W3T = Qb + (size_t)BB * CUT * HD;               // [192*1024]
  u16* VTg = W3T + (size_t)192 * 1024;                 // [B*64*T]   V transposed

  wtrans_k<<<768, 256, 0, stream>>>(Wk, Wv, Wq, W3T);
  proj_k<<<256, 256, 0, stream>>>(x, W3T, bk, bv, bq, Kb, Vb, Qb);
  vtrans_k<<<512, 256, 0, stream>>>(Vb, VTg);
  attn_k<<<dim3(CUT / 16, BB), 512, 0, stream>>>(Qb, Kb, VTg, out);
}